// Round 11
// baseline (345.550 us; speedup 1.0000x reference)
//
#include <hip/hip_runtime.h>

#define NF 64        // IN_F == HID_F == 64
#define BKSH 9       // bucket = dst >> 9 (512 nodes/bucket)
#define BKN 512      // nodes per bucket
#define SB 256       // superblocks (edge partitions)

typedef unsigned short u16;
typedef __attribute__((ext_vector_type(8))) short bf16x8;
typedef __attribute__((ext_vector_type(4))) float f32x4;

__device__ __forceinline__ float bf2f(unsigned h) {
    return __uint_as_float(h << 16);
}
__device__ __forceinline__ u16 f2bf(float x) {   // round-to-nearest-even
    unsigned u = __float_as_uint(x);
    return (u16)((u + 0x7FFFu + ((u >> 16) & 1u)) >> 16);
}

// ============ CSR build: two-phase radix partition ============
// LESSONS ledger: no __threadfence last-block fusion (r6: +32us); no
// grid-shrinking fusion of streaming work (r5: +35us); no barrier-coupled
// fusion of gather phases with compute (r7: +18us); gather-table rows MUST
// be 128B-aligned (r9: 64B offset doubles FETCH, +76us) -> 256B-padded ws.
// r10: scaled gather tables (Ya/Yb) eliminated -- dinv[s] applied per-edge
// from the L2-resident 400KB dinv table (fma instead of add, free).

__launch_bounds__(256)
__global__ void radix_count(const int* __restrict__ dst, int* __restrict__ hist,
                            int* __restrict__ bucket_total, int E, int epb, int nbuk) {
    __shared__ int bins[BKN];
    int tid = threadIdx.x, sb = blockIdx.x;
    for (int i = tid; i < nbuk; i += 256) bins[i] = 0;
    __syncthreads();
    int base = sb * epb;
    int end = min(base + epb, E);
    for (int e = base + tid; e < end; e += 256)
        atomicAdd(&bins[dst[e] >> BKSH], 1);
    __syncthreads();
    for (int i = tid; i < nbuk; i += 256) {
        int c = bins[i];
        hist[i * SB + sb] = c;
        if (c) atomicAdd(&bucket_total[i], c);
    }
}

__global__ void hist_scan(int* __restrict__ hist, const int* __restrict__ bucket_total,
                          int nbuk) {
    __shared__ int s[256];
    int b = blockIdx.x, tid = threadIdx.x;
    // pass 1: in-block exclusive bucket base
    int bv = (tid < nbuk) ? bucket_total[tid] : 0;
    s[tid] = bv; __syncthreads();
    for (int off = 1; off < 256; off <<= 1) {
        int t = (tid >= off) ? s[tid - off] : 0;
        __syncthreads();
        s[tid] += t;
        __syncthreads();
    }
    int bbase = s[b] - bucket_total[b];
    __syncthreads();
    // pass 2: scan this bucket's per-superblock counts
    int v = hist[b * SB + tid];
    s[tid] = v; __syncthreads();
    for (int off = 1; off < 256; off <<= 1) {
        int t = (tid >= off) ? s[tid - off] : 0;
        __syncthreads();
        s[tid] += t;
        __syncthreads();
    }
    hist[b * SB + tid] = bbase + s[tid] - v;
}

__launch_bounds__(256)
__global__ void radix_scatter(const int* __restrict__ src, const int* __restrict__ dst,
                              const int* __restrict__ hist, int* __restrict__ tmp,
                              int E, int epb, int nbuk) {
    __shared__ int cur[BKN];
    int tid = threadIdx.x, sb = blockIdx.x;
    for (int i = tid; i < nbuk; i += 256) cur[i] = hist[i * SB + sb];
    __syncthreads();
    int base = sb * epb;
    int end = min(base + epb, E);
    for (int e = base + tid; e < end; e += 256) {
        int d = dst[e];
        int b = d >> BKSH;
        int pos = atomicAdd(&cur[b], 1);
        tmp[pos] = ((d & (BKN - 1)) << 17) | src[e];
    }
}

__launch_bounds__(256)
__global__ void radix_build(const int* __restrict__ tmp, const int* __restrict__ bucket_total,
                            int* __restrict__ csr_src, int* __restrict__ rowptr,
                            float* __restrict__ dinv, int N, int nbuk) {
    __shared__ int cnt[BKN], excl[BKN], cur[BKN];
    __shared__ int s[256];
    int b = blockIdx.x, tid = threadIdx.x;
    // in-block bucket prefix
    int bv = (tid < nbuk) ? bucket_total[tid] : 0;
    s[tid] = bv; __syncthreads();
    for (int off = 1; off < 256; off <<= 1) {
        int t = (tid >= off) ? s[tid - off] : 0;
        __syncthreads();
        s[tid] += t;
        __syncthreads();
    }
    int end = s[b];
    int beg = end - bucket_total[b];
    __syncthreads();
    cnt[tid] = 0; cnt[tid + 256] = 0;
    __syncthreads();
    for (int e = beg + tid; e < end; e += 256)
        atomicAdd(&cnt[(tmp[e] >> 17) & (BKN - 1)], 1);
    __syncthreads();
    int c0 = cnt[2 * tid], c1 = cnt[2 * tid + 1];
    int v = c0 + c1;
    s[tid] = v; __syncthreads();
    for (int off = 1; off < 256; off <<= 1) {
        int t = (tid >= off) ? s[tid - off] : 0;
        __syncthreads();
        s[tid] += t;
        __syncthreads();
    }
    int base2 = s[tid] - v;
    excl[2 * tid] = base2;
    excl[2 * tid + 1] = base2 + c0;
    cur[2 * tid] = 0; cur[2 * tid + 1] = 0;
    int node0 = b << BKSH;
    int n0 = node0 + 2 * tid, n1 = n0 + 1;
    if (n0 < N) { rowptr[n0] = beg + base2;      dinv[n0] = rsqrtf(fmaxf((float)c0, 1.0f)); }
    if (n1 < N) { rowptr[n1] = beg + base2 + c0; dinv[n1] = rsqrtf(fmaxf((float)c1, 1.0f)); }
    __syncthreads();
    for (int e = beg + tid; e < end; e += 256) {
        int vv = tmp[e];
        int dlow = (vv >> 17) & (BKN - 1);
        int pos = excl[dlow] + atomicAdd(&cur[dlow], 1);
        csr_src[beg + pos] = vv & 0x1FFFF;
    }
}

// ============ prescale: Fb = bf16(feat) (+ W transpose tail + sentinel) ============
__global__ void prescale(const float* __restrict__ X, u16* __restrict__ Fb,
                         const float* __restrict__ W1, const float* __restrict__ W2,
                         u16* __restrict__ Wt1, u16* __restrict__ Wt2,
                         int* __restrict__ rowptr, int N, int E, int total4) {
    int i = blockIdx.x * blockDim.x + threadIdx.x;
    if (i == 0) rowptr[N] = E;   // sentinel (consumed later by spmm_m1)
    if (i < total4) {
        float4 v = ((const float4*)X)[i];
        ushort4 yu;
        yu.x = f2bf(v.x); yu.y = f2bf(v.y); yu.z = f2bf(v.z); yu.w = f2bf(v.w);
        ((ushort4*)Fb)[i] = yu;
    }
    if (i < 192 * 64) {
        int k = i >> 6, c = i & 63;
        Wt1[(size_t)c * 192 + k] = f2bf(W1[i]);
    } else if (i < 192 * 64 + 192 * 32) {
        int j = i - 192 * 64;
        int k = j >> 5, c = j & 31;
        Wt2[(size_t)c * 192 + k] = f2bf(W2[j]);
    }
}

// ============ scaled gather: acc[j] = sum_s X[s][j] * dinv[s] ============
// 8 lanes/node, x8 unroll, uint4 index loads (round-3 proven MLP structure).
// dinv[s] is a 4B load from the L2-resident 400KB degree table, broadcast
// across the 8-lane group; fma replaces add, so VALU count is unchanged.

#define ACC8S(A, u, d) \
    A[0] = fmaf(bf2f(u.x & 0xFFFFu), d, A[0]); A[1] = fmaf(bf2f(u.x >> 16), d, A[1]); \
    A[2] = fmaf(bf2f(u.y & 0xFFFFu), d, A[2]); A[3] = fmaf(bf2f(u.y >> 16), d, A[3]); \
    A[4] = fmaf(bf2f(u.z & 0xFFFFu), d, A[4]); A[5] = fmaf(bf2f(u.z >> 16), d, A[5]); \
    A[6] = fmaf(bf2f(u.w & 0xFFFFu), d, A[6]); A[7] = fmaf(bf2f(u.w >> 16), d, A[7]);

__device__ __forceinline__ void gather8s(const u16* __restrict__ Yf,
                                         const int* __restrict__ csr_src,
                                         const float* __restrict__ dinv,
                                         int beg, int end, float* __restrict__ out) {
    float acc[8], acc2[8];
#pragma unroll
    for (int j = 0; j < 8; ++j) { acc[j] = 0.f; acc2[j] = 0.f; }
    int e = beg;
    int pre = min(end, (beg + 3) & ~3);            // align e to 4 for uint4 idx loads
    for (; e < pre; ++e) {
        int s = csr_src[e];
        float d = dinv[s];
        uint4 u = *(const uint4*)(Yf + (size_t)s * NF);
        ACC8S(acc, u, d);
    }
    for (; e + 8 <= end; e += 8) {
        uint4 sA = *(const uint4*)(csr_src + e);
        uint4 sB = *(const uint4*)(csr_src + e + 4);
        float d0 = dinv[sA.x], d1 = dinv[sA.y], d2 = dinv[sA.z], d3 = dinv[sA.w];
        float d4 = dinv[sB.x], d5 = dinv[sB.y], d6 = dinv[sB.z], d7 = dinv[sB.w];
        uint4 u0 = *(const uint4*)(Yf + (size_t)sA.x * NF);
        uint4 u1 = *(const uint4*)(Yf + (size_t)sA.y * NF);
        uint4 u2 = *(const uint4*)(Yf + (size_t)sA.z * NF);
        uint4 u3 = *(const uint4*)(Yf + (size_t)sA.w * NF);
        uint4 u4 = *(const uint4*)(Yf + (size_t)sB.x * NF);
        uint4 u5 = *(const uint4*)(Yf + (size_t)sB.y * NF);
        uint4 u6 = *(const uint4*)(Yf + (size_t)sB.z * NF);
        uint4 u7 = *(const uint4*)(Yf + (size_t)sB.w * NF);
        ACC8S(acc, u0, d0); ACC8S(acc2, u1, d1); ACC8S(acc, u2, d2); ACC8S(acc2, u3, d3);
        ACC8S(acc, u4, d4); ACC8S(acc2, u5, d5); ACC8S(acc, u6, d6); ACC8S(acc2, u7, d7);
    }
    if (e + 4 <= end) {
        uint4 sA = *(const uint4*)(csr_src + e);
        float d0 = dinv[sA.x], d1 = dinv[sA.y], d2 = dinv[sA.z], d3 = dinv[sA.w];
        uint4 u0 = *(const uint4*)(Yf + (size_t)sA.x * NF);
        uint4 u1 = *(const uint4*)(Yf + (size_t)sA.y * NF);
        uint4 u2 = *(const uint4*)(Yf + (size_t)sA.z * NF);
        uint4 u3 = *(const uint4*)(Yf + (size_t)sA.w * NF);
        ACC8S(acc, u0, d0); ACC8S(acc2, u1, d1); ACC8S(acc, u2, d2); ACC8S(acc2, u3, d3);
        e += 4;
    }
    if (e + 2 <= end) {
        int2 sA = *(const int2*)(csr_src + e);
        float d0 = dinv[sA.x], d1 = dinv[sA.y];
        uint4 u0 = *(const uint4*)(Yf + (size_t)sA.x * NF);
        uint4 u1 = *(const uint4*)(Yf + (size_t)sA.y * NF);
        ACC8S(acc, u0, d0); ACC8S(acc2, u1, d1);
        e += 2;
    }
    if (e < end) {
        int s = csr_src[e];
        float d = dinv[s];
        uint4 u = *(const uint4*)(Yf + (size_t)s * NF);
        ACC8S(acc, u, d);
    }
#pragma unroll
    for (int j = 0; j < 8; ++j) out[j] = acc[j] + acc2[j];
}

// mode 1: X1b = bf16(-acc*dinv[node]);  acc = sum X0[s]*dinv[s]  (X0 = Fb or Hb)
__launch_bounds__(256)
__global__ void spmm_m1(const u16* __restrict__ X0t, const int* __restrict__ rowptr,
                        const int* __restrict__ csr_src, const float* __restrict__ dinv,
                        u16* __restrict__ X1b, int n) {
    int node = (int)((blockIdx.x * blockDim.x + threadIdx.x) >> 3);
    if (node >= n) return;
    int fl = (threadIdx.x & 7) << 3;
    float acc[8];
    gather8s(X0t + fl, csr_src, dinv, rowptr[node], rowptr[node + 1], acc);
    float dn = dinv[node];
    float r[8];
#pragma unroll
    for (int j = 0; j < 8; ++j) r[j] = -acc[j] * dn;
    uint4 ub;
    ub.x = (unsigned)f2bf(r[0]) | ((unsigned)f2bf(r[1]) << 16);
    ub.y = (unsigned)f2bf(r[2]) | ((unsigned)f2bf(r[3]) << 16);
    ub.z = (unsigned)f2bf(r[4]) | ((unsigned)f2bf(r[5]) << 16);
    ub.w = (unsigned)f2bf(r[6]) | ((unsigned)f2bf(r[7]) << 16);
    *(uint4*)(X1b + (size_t)node * NF + fl) = ub;
}

// mode 2: X2b = bf16(-2*acc*dinv[node] - Xprev);  acc = sum X1b[s]*dinv[s]
__launch_bounds__(256)
__global__ void spmm_m2(const u16* __restrict__ X1b, const int* __restrict__ rowptr,
                        const int* __restrict__ csr_src, const float* __restrict__ dinv,
                        const u16* __restrict__ Xprev, u16* __restrict__ X2b, int n) {
    int node = (int)((blockIdx.x * blockDim.x + threadIdx.x) >> 3);
    if (node >= n) return;
    int fl = (threadIdx.x & 7) << 3;
    float acc[8];
    gather8s(X1b + fl, csr_src, dinv, rowptr[node], rowptr[node + 1], acc);
    float dn = dinv[node];
    uint4 up = *(const uint4*)(Xprev + (size_t)node * NF + fl);
    float xp[8];
    xp[0] = bf2f(up.x & 0xFFFFu); xp[1] = bf2f(up.x >> 16);
    xp[2] = bf2f(up.y & 0xFFFFu); xp[3] = bf2f(up.y >> 16);
    xp[4] = bf2f(up.z & 0xFFFFu); xp[5] = bf2f(up.z >> 16);
    xp[6] = bf2f(up.w & 0xFFFFu); xp[7] = bf2f(up.w >> 16);
    float r[8];
#pragma unroll
    for (int j = 0; j < 8; ++j) r[j] = -2.f * acc[j] * dn - xp[j];
    uint4 uy;
    uy.x = (unsigned)f2bf(r[0]) | ((unsigned)f2bf(r[1]) << 16);
    uy.y = (unsigned)f2bf(r[2]) | ((unsigned)f2bf(r[3]) << 16);
    uy.z = (unsigned)f2bf(r[4]) | ((unsigned)f2bf(r[5]) << 16);
    uy.w = (unsigned)f2bf(r[6]) | ((unsigned)f2bf(r[7]) << 16);
    *(uint4*)(X2b + (size_t)node * NF + fl) = uy;
}

// ============ GEMM v6 (MFMA): C[N x OUTF] = [X0b|X1b|X2b] @ W + b ============
// Wave = 16 nodes; block = 4 waves = 64 nodes. Layer1 (OUTF=64): writes
// Hb=bf16(relu(H)) only (Ya eliminated r10). Layer2: fp32 out.
template <int OUTF>
__launch_bounds__(256)
__global__ void gemm_mfma(const u16* __restrict__ X0b, const u16* __restrict__ X1b,
                          const u16* __restrict__ X2b, const u16* __restrict__ Wt,
                          const float* __restrict__ bias,
                          float* __restrict__ outp, u16* __restrict__ Hb,
                          int n, int do_relu) {
    constexpr int NT = OUTF / 16;   // 4 or 2 N-tiles
    const int wave = threadIdx.x >> 6;
    const int lane = threadIdx.x & 63;
    const int node0 = blockIdx.x * 64 + wave * 16;
    const int m = lane & 15;
    const int q = lane >> 4;
    const int arow = min(node0 + m, n - 1);   // OOB rows only corrupt unstored D rows

    union U8 { uint4 u; bf16x8 v; };

    f32x4 acc[NT];
#pragma unroll
    for (int t = 0; t < NT; ++t) acc[t] = (f32x4){0.f, 0.f, 0.f, 0.f};

    const u16* Xs[3] = {X0b, X1b, X2b};
#pragma unroll
    for (int p = 0; p < 3; ++p) {
        const u16* __restrict__ Xc = Xs[p];
#pragma unroll
        for (int h = 0; h < 2; ++h) {
            U8 a;
            a.u = *(const uint4*)(Xc + (size_t)arow * 64 + h * 32 + q * 8);
#pragma unroll
            for (int t = 0; t < NT; ++t) {
                U8 b;
                b.u = *(const uint4*)(Wt + (size_t)(t * 16 + m) * 192 + p * 64 + h * 32 + q * 8);
                acc[t] = __builtin_amdgcn_mfma_f32_16x16x32_bf16(a.v, b.v, acc[t], 0, 0, 0);
            }
        }
    }

    // epilogue: lane holds D[row=node0+q*4+r][col=t*16+m]
#pragma unroll
    for (int t = 0; t < NT; ++t) {
        int col = t * 16 + m;
        float bv = bias[col];
#pragma unroll
        for (int r = 0; r < 4; ++r) {
            int row = node0 + q * 4 + r;
            if (row < n) {
                float v = acc[t][r] + bv;
                if (do_relu) v = fmaxf(v, 0.f);
                if (OUTF == 64) {
                    Hb[(size_t)row * 64 + col] = f2bf(v);
                } else {
                    outp[(size_t)row * 32 + col] = v;
                }
            }
        }
    }
}

extern "C" void kernel_launch(void* const* d_in, const int* in_sizes, int n_in,
                              void* d_out, int out_size, void* d_ws, size_t ws_size,
                              hipStream_t stream) {
    const float* feat = (const float*)d_in[0];
    const int*   src  = (const int*)d_in[1];
    const int*   dst  = (const int*)d_in[2];
    const float* W1   = (const float*)d_in[3];
    const float* b1   = (const float*)d_in[4];
    const float* W2   = (const float*)d_in[5];
    const float* b2   = (const float*)d_in[6];
    float* out = (float*)d_out;

    const int N = in_sizes[0] / NF;   // 100000
    const int E = in_sizes[1];        // 1600000
    const size_t NFtot = (size_t)N * NF;
    const int nbuk = (N + BKN - 1) >> BKSH;   // 196
    const int epb = (E + SB - 1) / SB;        // 6250

    // workspace layout — every chunk padded to 256 B (r9 lesson: bf16
    // feature tables must keep 128B-aligned rows).
    char* p = (char*)d_ws;
    auto alloc = [&p](size_t bytes) {
        char* q = p;
        p += (bytes + 255) & ~(size_t)255;
        return q;
    };
    int* hist         = (int*)alloc((size_t)BKN * SB * 4);
    int* bucket_total = (int*)alloc((BKN + 1) * 4);
    int* rowptr       = (int*)alloc(((size_t)N + 1) * 4);
    int* csr_src      = (int*)alloc((size_t)E * 4);
    float* dinv       = (float*)alloc((size_t)N * 4);
    u16* Wt1          = (u16*)alloc(192 * 64 * 2);
    u16* Wt2          = (u16*)alloc(192 * 32 * 2);
    u16* X1b          = (u16*)alloc(NFtot * 2);   // bf16(X1): gather table for m2 + gemm operand
    u16* X2b          = (u16*)alloc(NFtot * 2);   // bf16(X2) gemm operand
    u16* Fb           = (u16*)alloc(NFtot * 2);   // bf16(feat): layer-1 gather table + operand
    u16* Hb           = (u16*)alloc(NFtot * 2);   // bf16(relu(H)): layer-2 gather table + operand
    int* tmp = (int*)X2b;          // alias X2b; consumed by radix_build before spmm_m2 writes X2b

    const int TB = 256;
    dim3 blk(TB);
    dim3 gW8(((size_t)N * 8 + TB - 1) / TB);    // 8 lanes per node
    dim3 gPre(((size_t)N * 16 + TB - 1) / TB);
    dim3 gGemm((N + 63) / 64);

    // ---- CSR build (radix partition; 4 kernels, no fences, no 1-block scan) ----
    hipMemsetAsync(bucket_total, 0, (size_t)(BKN + 1) * sizeof(int), stream);
    radix_count<<<dim3(SB), blk, 0, stream>>>(dst, hist, bucket_total, E, epb, nbuk);
    hist_scan<<<dim3(nbuk), blk, 0, stream>>>(hist, bucket_total, nbuk);
    radix_scatter<<<dim3(SB), blk, 0, stream>>>(src, dst, hist, tmp, E, epb, nbuk);
    radix_build<<<dim3(nbuk), blk, 0, stream>>>(tmp, bucket_total, csr_src, rowptr, dinv, N, nbuk);

    // ---- prescale (Fb) + weight transpose + rowptr sentinel ----
    prescale<<<gPre, blk, 0, stream>>>(feat, Fb, W1, W2, Wt1, Wt2,
                                       rowptr, N, E, (int)(N * 16));

    // ---- layer 1 ----
    spmm_m1<<<gW8, blk, 0, stream>>>(Fb, rowptr, csr_src, dinv, X1b, N);
    spmm_m2<<<gW8, blk, 0, stream>>>(X1b, rowptr, csr_src, dinv, Fb, X2b, N);
    gemm_mfma<64><<<gGemm, blk, 0, stream>>>(Fb, X1b, X2b, Wt1, b1,
                                             nullptr, Hb, N, 1);

    // ---- layer 2 ----
    spmm_m1<<<gW8, blk, 0, stream>>>(Hb, rowptr, csr_src, dinv, X1b, N);
    spmm_m2<<<gW8, blk, 0, stream>>>(X1b, rowptr, csr_src, dinv, Hb, X2b, N);
    gemm_mfma<32><<<gGemm, blk, 0, stream>>>(Hb, X1b, X2b, Wt2, b2,
                                             out, nullptr, N, 0);
}